// Round 3
// baseline (455.236 us; speedup 1.0000x reference)
//
#include <hip/hip_runtime.h>
#include <math.h>

// TemporalEncoder: out[t, b, d] = (t == floor(sigmoid(x[b,d]) * (T-1))) ? 1 : 0
// B=256, D=4096, T=100. Output 419 MB fp32 -> pure write-BW bound (~67 us at
// 6.3 TB/s achievable).
//
// R1 lesson: per-element loop over t -> scattered 1KB bursts, 1.0 TB/s.
// R2 lesson: one load->one store per thread is latency-shaped (~3.1 TB/s);
//            fillBuffer (6.3 TB/s) is a persistent grid-stride store loop.
// R3: pass 2 becomes fill-shaped: grid-stride over 64B output chunks, each
//     iter = 1 uint4 L2-hit load of 16 spike-time bytes + 4 back-to-back
//     dwordx4 stores. n = 2^20 makes t/ci a shift/mask (no divides).

typedef __attribute__((ext_vector_type(4))) float f32x4;

__device__ __forceinline__ float sigmoidf(float x) {
    return 1.0f / (1.0f + expf(-x));  // 0-ulp match vs np ref (R1 absmax=0)
}

// Pass 1: spike times, packed 4/uint. n assumed %4==0 (n = 2^20 here).
__global__ __launch_bounds__(256) void spike_time_kernel(
    const float* __restrict__ x, unsigned int* __restrict__ st,
    int n, float tm1) {
    const int e = (blockIdx.x * 256 + threadIdx.x) * 4;
    if (e + 3 < n) {
        f32x4 v = *reinterpret_cast<const f32x4*>(x + e);
        unsigned int s0 = (unsigned int)(int)(sigmoidf(v.x) * tm1);
        unsigned int s1 = (unsigned int)(int)(sigmoidf(v.y) * tm1);
        unsigned int s2 = (unsigned int)(int)(sigmoidf(v.z) * tm1);
        unsigned int s3 = (unsigned int)(int)(sigmoidf(v.w) * tm1);
        st[e >> 2] = s0 | (s1 << 8) | (s2 << 16) | (s3 << 24);
    } else {
        unsigned char* stb = (unsigned char*)st;
        for (int i = e; i < n; ++i)
            stb[i] = (unsigned char)(int)(sigmoidf(x[i]) * tm1);
    }
}

// Pass 2 (fast path, n = 2^lg): grid-stride over 64-byte chunks.
// chunk c: t = c >> (lg-4), ci = c & ((n/16)-1); reads st dwords
// [ci*4 .. ci*4+3], writes out[t*n + ci*16 .. +15].
__global__ __launch_bounds__(256) void write_onehot_fill(
    const unsigned int* __restrict__ st, float* __restrict__ out,
    int lg /* log2(n) */, long total_chunks) {
    const int shift = lg - 4;
    const unsigned int mask = (1u << shift) - 1u;
    const long stride = (long)gridDim.x * 256;
    for (long c = (long)blockIdx.x * 256 + threadIdx.x; c < total_chunks;
         c += stride) {
        const unsigned int t = (unsigned int)(c >> shift);
        const unsigned int ci = (unsigned int)c & mask;
        const uint4 w = *reinterpret_cast<const uint4*>(st + (size_t)ci * 4);
        float* p = out + ((size_t)t << lg) + (size_t)ci * 16;
        f32x4 o;
        o.x = ((w.x & 0xFFu) == t) ? 1.0f : 0.0f;
        o.y = (((w.x >> 8) & 0xFFu) == t) ? 1.0f : 0.0f;
        o.z = (((w.x >> 16) & 0xFFu) == t) ? 1.0f : 0.0f;
        o.w = ((w.x >> 24) == t) ? 1.0f : 0.0f;
        reinterpret_cast<f32x4*>(p)[0] = o;
        o.x = ((w.y & 0xFFu) == t) ? 1.0f : 0.0f;
        o.y = (((w.y >> 8) & 0xFFu) == t) ? 1.0f : 0.0f;
        o.z = (((w.y >> 16) & 0xFFu) == t) ? 1.0f : 0.0f;
        o.w = ((w.y >> 24) == t) ? 1.0f : 0.0f;
        reinterpret_cast<f32x4*>(p)[1] = o;
        o.x = ((w.z & 0xFFu) == t) ? 1.0f : 0.0f;
        o.y = (((w.z >> 8) & 0xFFu) == t) ? 1.0f : 0.0f;
        o.z = (((w.z >> 16) & 0xFFu) == t) ? 1.0f : 0.0f;
        o.w = ((w.z >> 24) == t) ? 1.0f : 0.0f;
        reinterpret_cast<f32x4*>(p)[2] = o;
        o.x = ((w.w & 0xFFu) == t) ? 1.0f : 0.0f;
        o.y = (((w.w >> 8) & 0xFFu) == t) ? 1.0f : 0.0f;
        o.z = (((w.w >> 16) & 0xFFu) == t) ? 1.0f : 0.0f;
        o.w = ((w.w >> 24) == t) ? 1.0f : 0.0f;
        reinterpret_cast<f32x4*>(p)[3] = o;
    }
}

// Fallback (non-pow2 n or tiny ws): fused recompute, one float4/thread.
__global__ __launch_bounds__(256) void fused_onehot_kernel(
    const float* __restrict__ x, float* __restrict__ out, int n, float tm1) {
    const int t = blockIdx.y;
    const int e = (blockIdx.x * 256 + threadIdx.x) * 4;
    if (e + 3 < n) {
        f32x4 v = *reinterpret_cast<const f32x4*>(x + e);
        f32x4 o;
        o.x = ((int)(sigmoidf(v.x) * tm1) == t) ? 1.0f : 0.0f;
        o.y = ((int)(sigmoidf(v.y) * tm1) == t) ? 1.0f : 0.0f;
        o.z = ((int)(sigmoidf(v.z) * tm1) == t) ? 1.0f : 0.0f;
        o.w = ((int)(sigmoidf(v.w) * tm1) == t) ? 1.0f : 0.0f;
        *reinterpret_cast<f32x4*>(out + (size_t)t * n + e) = o;
    } else {
        for (int i = e; i < n; ++i)
            out[(size_t)t * n + i] = ((int)(sigmoidf(x[i]) * tm1) == t) ? 1.0f : 0.0f;
    }
}

extern "C" void kernel_launch(void* const* d_in, const int* in_sizes, int n_in,
                              void* d_out, int out_size, void* d_ws, size_t ws_size,
                              hipStream_t stream) {
    const float* x = (const float*)d_in[0];
    float* out = (float*)d_out;
    const int n = in_sizes[0];        // B*D = 1048576 = 2^20
    const int T = out_size / n;       // 100
    const float tm1 = (float)(T - 1);

    const bool pow2 = (n & (n - 1)) == 0 && n >= 16;
    if (pow2 && ws_size >= (size_t)n && T <= 256) {
        int lg = 0;
        while ((1 << lg) < n) ++lg;
        unsigned int* st = (unsigned int*)d_ws;
        const int blocks1 = (n / 4 + 255) / 256;
        spike_time_kernel<<<blocks1, 256, 0, stream>>>(x, st, n, tm1);
        const long total_chunks = (long)out_size / 16;
        // 8 blocks/CU * 256 CUs: persistent fill-shaped grid (~12.5 iters/thread)
        write_onehot_fill<<<2048, 256, 0, stream>>>(st, out, lg, total_chunks);
    } else {
        const int blocks_x = ((n + 3) / 4 + 255) / 256;
        dim3 grid(blocks_x, T);
        fused_onehot_kernel<<<grid, 256, 0, stream>>>(x, out, n, tm1);
    }
}

// Round 4
// 423.061 us; speedup vs baseline: 1.0761x; 1.0761x over previous
//
#include <hip/hip_runtime.h>
#include <math.h>

// TemporalEncoder: out[t, b, d] = (t == floor(sigmoid(x[b,d]) * (T-1))) ? 1 : 0
// B=256, D=4096, T=100. Output 419 MB fp32 -> pure write-BW bound (~67 us at
// 6.3 TB/s). Timed window also contains the harness 0xAA poison fill (~267 us)
// which we cannot remove; our budget is everything above that.
//
// R1: per-element t-loop -> scattered 1KB bursts, ~159 us (2.6 TB/s).
// R2: coalesced one-load+one-store per thread -> ~134 us (latency-shaped).
// R3: 64B-per-lane grid-stride -> 64B inter-lane stride = UNCOALESCED stores,
//     ~188 us. Lesson: lane l must own 16B at wave_base + l*16.
// R4: persistent + coalesced. Grid chosen so stride S (in float4 units) is a
//     multiple of the plane size n/4 -> plane offset ci = c & mask is loop-
//     invariant -> each thread loads its 4 spike bytes ONCE, then issues ~50
//     back-to-back coalesced dwordx4 stores. Pure fill with a pattern reg.

typedef __attribute__((ext_vector_type(4))) float f32x4;

__device__ __forceinline__ float sigmoidf(float x) {
    return 1.0f / (1.0f + expf(-x));  // 0-ulp match vs np ref (R1 absmax=0)
}

// Pass 1: spike times, 4 packed per uint. n % 4 == 0 on fast path.
__global__ __launch_bounds__(256) void spike_time_kernel(
    const float* __restrict__ x, unsigned int* __restrict__ st,
    int n, float tm1) {
    const int e = (blockIdx.x * 256 + threadIdx.x) * 4;
    if (e + 3 < n) {
        f32x4 v = *reinterpret_cast<const f32x4*>(x + e);
        unsigned int s0 = (unsigned int)(int)(sigmoidf(v.x) * tm1);
        unsigned int s1 = (unsigned int)(int)(sigmoidf(v.y) * tm1);
        unsigned int s2 = (unsigned int)(int)(sigmoidf(v.z) * tm1);
        unsigned int s3 = (unsigned int)(int)(sigmoidf(v.w) * tm1);
        st[e >> 2] = s0 | (s1 << 8) | (s2 << 16) | (s3 << 24);
    } else {
        unsigned char* stb = (unsigned char*)st;
        for (int i = e; i < n; ++i)
            stb[i] = (unsigned char)(int)(sigmoidf(x[i]) * tm1);
    }
}

// Pass 2: persistent, coalesced. Requires S % (1<<shift) == 0 where
// shift = log2(n/4): then ci = gid & mask is invariant over the loop and the
// spike word is loaded exactly once per thread.
__global__ __launch_bounds__(256) void write_onehot_persist(
    const unsigned int* __restrict__ st, float* __restrict__ out,
    int shift, long total4) {
    const long gid = (long)blockIdx.x * 256 + threadIdx.x;
    const long S = (long)gridDim.x * 256;
    const unsigned int mask = (1u << shift) - 1u;
    const unsigned int w = st[(unsigned int)gid & mask];
    const unsigned int b0 = w & 0xFFu;
    const unsigned int b1 = (w >> 8) & 0xFFu;
    const unsigned int b2 = (w >> 16) & 0xFFu;
    const unsigned int b3 = w >> 24;
    f32x4* out4 = reinterpret_cast<f32x4*>(out);
#pragma unroll 4
    for (long c = gid; c < total4; c += S) {
        const unsigned int t = (unsigned int)(c >> shift);
        f32x4 o;
        o.x = (b0 == t) ? 1.0f : 0.0f;
        o.y = (b1 == t) ? 1.0f : 0.0f;
        o.z = (b2 == t) ? 1.0f : 0.0f;
        o.w = (b3 == t) ? 1.0f : 0.0f;
        out4[c] = o;
    }
}

// Fallback (non-pow2 n or tiny ws): fused recompute, one float4/thread.
__global__ __launch_bounds__(256) void fused_onehot_kernel(
    const float* __restrict__ x, float* __restrict__ out, int n, float tm1) {
    const int t = blockIdx.y;
    const int e = (blockIdx.x * 256 + threadIdx.x) * 4;
    if (e + 3 < n) {
        f32x4 v = *reinterpret_cast<const f32x4*>(x + e);
        f32x4 o;
        o.x = ((int)(sigmoidf(v.x) * tm1) == t) ? 1.0f : 0.0f;
        o.y = ((int)(sigmoidf(v.y) * tm1) == t) ? 1.0f : 0.0f;
        o.z = ((int)(sigmoidf(v.z) * tm1) == t) ? 1.0f : 0.0f;
        o.w = ((int)(sigmoidf(v.w) * tm1) == t) ? 1.0f : 0.0f;
        *reinterpret_cast<f32x4*>(out + (size_t)t * n + e) = o;
    } else {
        for (int i = e; i < n; ++i)
            out[(size_t)t * n + i] = ((int)(sigmoidf(x[i]) * tm1) == t) ? 1.0f : 0.0f;
    }
}

extern "C" void kernel_launch(void* const* d_in, const int* in_sizes, int n_in,
                              void* d_out, int out_size, void* d_ws, size_t ws_size,
                              hipStream_t stream) {
    const float* x = (const float*)d_in[0];
    float* out = (float*)d_out;
    const int n = in_sizes[0];        // B*D = 1048576 = 2^20
    const int T = out_size / n;       // 100
    const float tm1 = (float)(T - 1);

    const bool pow2 = (n & (n - 1)) == 0 && n >= 16;
    const int blocks2 = 2048;                  // 8 blocks/CU, 8192 waves
    const long S = (long)blocks2 * 256;        // grid-stride in float4 units
    int lg = 0;
    if (pow2) { while ((1 << lg) < n) ++lg; }
    const int shift = lg - 2;                  // log2(float4s per plane)
    const bool fast = pow2 && ws_size >= (size_t)n && T <= 256 &&
                      shift >= 0 && (S % (1L << shift)) == 0;
    if (fast) {
        unsigned int* st = (unsigned int*)d_ws;
        const int blocks1 = (n / 4 + 255) / 256;
        spike_time_kernel<<<blocks1, 256, 0, stream>>>(x, st, n, tm1);
        const long total4 = (long)out_size / 4;
        write_onehot_persist<<<blocks2, 256, 0, stream>>>(st, out, shift, total4);
    } else {
        const int blocks_x = ((n + 3) / 4 + 255) / 256;
        dim3 grid(blocks_x, T);
        fused_onehot_kernel<<<grid, 256, 0, stream>>>(x, out, n, tm1);
    }
}